// Round 6
// baseline (2915.924 us; speedup 1.0000x reference)
//
#include <hip/hip_runtime.h>

typedef unsigned short u16;
typedef __attribute__((ext_vector_type(8))) short short8;
typedef __attribute__((ext_vector_type(4))) float f32x4;

// ---------- sizes ----------
#define BB 64
#define SS 256
#define HH 1024
#define NG 3072                 // 3H
#define KK 1024
#define NOUT ((size_t)BB * SS * HH)

// ws layout (bytes)
#define OFF_GSUM 0ull
#define OFF_HB0 100663296ull
#define OFF_HB1 100794368ull
#define OFF_BAR 100925440ull
#define WS_NEED 100925568ull

__device__ __forceinline__ float bf2f_u(unsigned x) {
  unsigned u = x << 16;
  float f;
  __builtin_memcpy(&f, &u, 4);
  return f;
}
__device__ __forceinline__ u16 f2bf(float f) {
  unsigned u;
  __builtin_memcpy(&u, &f, 4);
  u = (u + 0x7fffu + ((u >> 16) & 1u)) >> 16;
  return (u16)u;
}
// pack 8 f32 -> short8 of bf16 (RTNE) via v_cvt_pk_bf16_f32
__device__ __forceinline__ short8 cvt8(f32x4 lo, f32x4 hi) {
  union { unsigned u[4]; short8 s; } r;
  asm("v_cvt_pk_bf16_f32 %0, %1, %2" : "=v"(r.u[0]) : "v"(lo[0]), "v"(lo[1]));
  asm("v_cvt_pk_bf16_f32 %0, %1, %2" : "=v"(r.u[1]) : "v"(lo[2]), "v"(lo[3]));
  asm("v_cvt_pk_bf16_f32 %0, %1, %2" : "=v"(r.u[2]) : "v"(hi[0]), "v"(hi[1]));
  asm("v_cvt_pk_bf16_f32 %0, %1, %2" : "=v"(r.u[3]) : "v"(hi[2]), "v"(hi[3]));
  return r.s;
}
__device__ __forceinline__ float sigmoidf_(float x) {
  return __builtin_amdgcn_rcpf(1.f + __expf(-x));
}
__device__ __forceinline__ float tanhf_(float x) {
  return 2.f * __builtin_amdgcn_rcpf(1.f + __expf(-2.f * x)) - 1.f;
}

typedef const __attribute__((address_space(1))) void* gcptr;
typedef __attribute__((address_space(3))) void* lptr;

// ================= GEMM (f32 inputs, bf16 MFMA): gsum = X@Wih^T + b_ih
//                   (+F0@Wf0^T + F1@Wf1^T + b_f0 + b_f1 on cols<2048)
// f32 tiles staged async via global_load_lds with XOR-swizzled SOURCE granules
// (LDS dest must stay linear); consume-side v_cvt_pk_bf16_f32 -> MFMA.
__global__ __launch_bounds__(256) void gemm_fused(
    const float* __restrict__ X, const float* __restrict__ F0, const float* __restrict__ F1,
    const float* __restrict__ Wih, const float* __restrict__ Wf0, const float* __restrict__ Wf1,
    const float* __restrict__ bih, const float* __restrict__ bf0, const float* __restrict__ bf1,
    u16* __restrict__ C) {
  __shared__ __align__(16) float ldsA[128 * 32];
  __shared__ __align__(16) float ldsB[128 * 32];
  const int t = threadIdx.x;
  const int nwg = gridDim.x;                  // 3072 (divisible by 8)
  const int cpx = nwg >> 3;
  const int wg = (blockIdx.x & 7) * cpx + (blockIdx.x >> 3);   // XCD-contiguous chunks
  const int ntn = NG / 128;                   // 24
  const int m0 = (wg / ntn) * 128;
  const int n0 = (wg % ntn) * 128;
  const int lane = t & 63, wv = t >> 6;
  const int wm = wv >> 1, wn = wv & 1;

  f32x4 acc[4][4] = {};

  // staging geometry: 4 calls/tile; call c, thread t -> slot idx = c*256+t,
  // row = idx>>3, granule q = idx&7 (16B = 4 floats). Source granule q^(row&7).
  const int nsrc = (n0 < 2048) ? 3 : 1;
  for (int src = 0; src < nsrc; ++src) {
    const float* Ap = (src == 0) ? X : ((src == 1) ? F0 : F1);
    const float* Wp = (src == 0) ? Wih : ((src == 1) ? Wf0 : Wf1);
    const float* Abase = Ap + (size_t)m0 * KK;
    const float* Wbase = Wp + (size_t)n0 * KK;
    for (int k0 = 0; k0 < KK; k0 += 32) {
#pragma unroll
      for (int c = 0; c < 4; ++c) {
        const int idx = c * 256 + t;
        const int row = idx >> 3, q = idx & 7;
        const int qs = q ^ (row & 7);
        __builtin_amdgcn_global_load_lds((gcptr)(Abase + (size_t)row * KK + k0 + qs * 4),
                                         (lptr)(&ldsA[idx * 4]), 16, 0, 0);
        __builtin_amdgcn_global_load_lds((gcptr)(Wbase + (size_t)row * KK + k0 + qs * 4),
                                         (lptr)(&ldsB[idx * 4]), 16, 0, 0);
      }
      __syncthreads();
      short8 af[4], bw[4];
      const int g0 = (lane >> 4) * 2;      // granule pair base for this lane
#pragma unroll
      for (int i = 0; i < 4; ++i) {
        {
          const int row = wm * 64 + i * 16 + (lane & 15);
          const int ga = g0 ^ (row & 7), gb = (g0 + 1) ^ (row & 7);
          f32x4 lo = *(const f32x4*)&ldsA[row * 32 + ga * 4];
          f32x4 hi = *(const f32x4*)&ldsA[row * 32 + gb * 4];
          af[i] = cvt8(lo, hi);
        }
        {
          const int row = wn * 64 + i * 16 + (lane & 15);
          const int ga = g0 ^ (row & 7), gb = (g0 + 1) ^ (row & 7);
          f32x4 lo = *(const f32x4*)&ldsB[row * 32 + ga * 4];
          f32x4 hi = *(const f32x4*)&ldsB[row * 32 + gb * 4];
          bw[i] = cvt8(lo, hi);
        }
      }
#pragma unroll
      for (int i = 0; i < 4; ++i)
#pragma unroll
        for (int j = 0; j < 4; ++j)
          acc[i][j] = __builtin_amdgcn_mfma_f32_16x16x32_bf16(af[i], bw[j], acc[i][j], 0, 0, 0);
      __syncthreads();
    }
  }
#pragma unroll
  for (int j = 0; j < 4; ++j) {
    const int col = n0 + wn * 64 + j * 16 + (lane & 15);
    float bias = bih[col];
    if (col < 2048) bias += bf0[col] + bf1[col];
#pragma unroll
    for (int i = 0; i < 4; ++i) {
      const int row = m0 + wm * 64 + i * 16 + (lane >> 4) * 4;
#pragma unroll
      for (int r = 0; r < 4; ++r)
        C[(size_t)(row + r) * NG + col] = f2bf(acc[i][j][r] + bias);
    }
  }
}

// ================= scan: weight-stationary persistent GRU ====================
// 64 WGs x 256 thr. WG w owns hidden cols [w*16, w*16+16). Whh strips r,i,n in LDS
// as [48 rows][2048B], full-rank XOR swizzle -> conflict-free (measured 0).
// h exchange: stores write-through (sc0 sc1); loads CACHED, made safe by an
// acquire-agent fence (inv-only) after the grid barrier. All L2 lines are clean
// during the loop (h/out stores write-through, gsum read-only) so inv loses nothing.
#define SB0() __builtin_amdgcn_sched_barrier(0)

#define ISSUE8(buf, bkk)                                                        \
  _Pragma("unroll")                                                             \
  for (int i_ = 0; i_ < 8; ++i_)                                                \
    asm volatile("global_load_dwordx4 %0, %1, off"                              \
                 : "=v"(buf[i_]) : "v"(ap + ((bkk) + i_) * 32));

#define CONSUME8(buf, bkk)                                                      \
  _Pragma("unroll")                                                             \
  for (int i_ = 0; i_ < 8; ++i_) {                                              \
    const int ko_ = ((bkk) + i_) * 64 + kb;                                     \
    short8 br_ = *(const short8*)(s0 + (ko_ ^ sw));                             \
    short8 bj_ = *(const short8*)(s1 + (ko_ ^ sw));                             \
    short8 bn_ = *(const short8*)(s2 + (ko_ ^ sw));                             \
    ar = __builtin_amdgcn_mfma_f32_16x16x32_bf16(buf[i_], br_, ar, 0, 0, 0);    \
    ai = __builtin_amdgcn_mfma_f32_16x16x32_bf16(buf[i_], bj_, ai, 0, 0, 0);    \
    an = __builtin_amdgcn_mfma_f32_16x16x32_bf16(buf[i_], bn_, an, 0, 0, 0);    \
  }

#define ISSUE_GSUM(snext)                                                       \
  _Pragma("unroll")                                                             \
  for (int r_ = 0; r_ < 4; ++r_) {                                              \
    const u16* gp_ = gsum + ((size_t)(mb + quad * 4 + r_) * 256 + (size_t)(snext)) * 3072 + jl; \
    asm volatile("global_load_ushort %0, %1, off" : "=v"(pgu[r_ * 3 + 0]) : "v"(gp_));          \
    asm volatile("global_load_ushort %0, %1, off" : "=v"(pgu[r_ * 3 + 1]) : "v"(gp_ + 1024));   \
    asm volatile("global_load_ushort %0, %1, off" : "=v"(pgu[r_ * 3 + 2]) : "v"(gp_ + 2048));   \
  }

__global__ __launch_bounds__(256, 1) void scan_kernel(
    const u16* __restrict__ gsum, const float* __restrict__ Whh, const float* __restrict__ bhh,
    u16* __restrict__ h0buf, u16* __restrict__ h1buf,
    float* __restrict__ out, unsigned* __restrict__ bar) {
  extern __shared__ u16 wlds[];  // 48*1024 bf16 = 96KB
  const int t = threadIdx.x, w = blockIdx.x;
  const int j0 = w * 16;
  // stage weights (once): row q = g*16+i <- Whh[g*1024 + j0 + i][:], f32 -> bf16, byte ^= (i<<4)
  for (int c = t; c < 48 * 128; c += 256) {
    int q = c >> 7, chunk = c & 127;
    int g = q >> 4, i = q & 15;
    const float* wf = Whh + ((size_t)(g * 1024 + j0 + i)) * 1024 + chunk * 8;
    short8 v = cvt8(*(const f32x4*)wf, *(const f32x4*)(wf + 4));
    *(short8*)((char*)wlds + q * 2048 + ((chunk * 16) ^ (i << 4))) = v;
  }
  const int lane = t & 63;
  const int bi = lane & 15;
  const int quad = lane >> 4;
  const int jl = j0 + bi;
  const int mb = (t >> 6) * 16;
  const float bhr = bhh[jl];
  const float bhi = bhh[1024 + jl];
  const float bhn = bhh[2048 + jl];
  __syncthreads();

  float hreg[4] = {0.f, 0.f, 0.f, 0.f};

  const int kb = quad * 16;                 // byte offset of lane's 16B k-chunk
  const int sw = bi << 4;                   // full-rank XOR swizzle
  const char* wbytes = (const char*)wlds;
  const char* s0 = wbytes + (size_t)(0 + bi) * 2048;
  const char* s1 = wbytes + (size_t)(16 + bi) * 2048;
  const char* s2 = wbytes + (size_t)(32 + bi) * 2048;

  unsigned pgu[12];
  ISSUE_GSUM(0);
  asm volatile("s_waitcnt vmcnt(0)" ::: "memory");
  SB0();

  short8 aA[8], aB[8], aC[8], aD[8];
  for (int s = 0; s < 256; ++s) {
    f32x4 ar = {0.f, 0.f, 0.f, 0.f};
    f32x4 ai = {0.f, 0.f, 0.f, 0.f};
    f32x4 an = {0.f, 0.f, 0.f, 0.f};
    if (s > 0) {
      // outstanding here: exactly the 32 h loads (fence drained everything older)
      asm volatile("s_waitcnt vmcnt(24)" ::: "memory");
      SB0();
      CONSUME8(aA, 0);
      asm volatile("s_waitcnt vmcnt(16)" ::: "memory");
      SB0();
      CONSUME8(aB, 8);
      asm volatile("s_waitcnt vmcnt(8)" ::: "memory");
      SB0();
      CONSUME8(aC, 16);
      asm volatile("s_waitcnt vmcnt(0)" ::: "memory");
      SB0();
      CONSUME8(aD, 24);
      SB0();
    }
    u16* hw = (s & 1) ? h0buf : h1buf;
    float hy4[4];
    unsigned hv4[4];
#pragma unroll
    for (int r = 0; r < 4; ++r) {
      float rg = sigmoidf_(bf2f_u(pgu[r * 3 + 0]) + ar[r] + bhr);
      float ig = sigmoidf_(bf2f_u(pgu[r * 3 + 1]) + ai[r] + bhi);
      float ng = tanhf_(bf2f_u(pgu[r * 3 + 2]) + rg * (an[r] + bhn));
      float hy = ng + ig * (hreg[r] - ng);
      hreg[r] = hy;
      hy4[r] = hy;
      hv4[r] = (unsigned)f2bf(hy);
    }
    // order matters for vmcnt(16): ALL 4 h stores first, then 4 out stores.
    if (s < 255) {
#pragma unroll
      for (int r = 0; r < 4; ++r) {
        int b = mb + quad * 4 + r;
        asm volatile("global_store_short %0, %1, off sc0 sc1"
                     :: "v"(hw + (size_t)b * 1024 + jl), "v"(hv4[r]) : "memory");
      }
    }
#pragma unroll
    for (int r = 0; r < 4; ++r) {
      int b = mb + quad * 4 + r;
      size_t m = (size_t)b * 256 + s;
      asm volatile("global_store_dword %0, %1, off sc0 sc1"
                   :: "v"(out + m * 1024 + jl), "v"(hy4[r]) : "memory");
    }
    if (s < 255) {
      ISSUE_GSUM(s + 1);
      // outstanding: [4 hst][4 out][12 gsum] -> vmcnt(16) retires exactly the h stores
      asm volatile("s_waitcnt vmcnt(16)" ::: "memory");
      SB0();
      __builtin_amdgcn_s_barrier();          // raw: no compiler vmcnt(0) drain
      if (t == 0) {
        unsigned one = 1;
        asm volatile("global_atomic_add %0, %1, off" :: "v"(bar), "v"(one) : "memory");
        unsigned v;
        for (;;) {
          asm volatile("global_load_dword %0, %1, off sc0 sc1\n\ts_waitcnt vmcnt(0)"
                       : "=v"(v) : "v"(bar) : "memory");
          if (v >= (unsigned)(64 * (s + 1))) break;
          __builtin_amdgcn_s_sleep(1);
        }
      }
      __builtin_amdgcn_s_barrier();
      SB0();
      // acquire: invalidate stale L1/L2 h lines (inv-only; all L2 lines clean)
      __builtin_amdgcn_fence(__ATOMIC_ACQUIRE, "agent");
      SB0();
      // issue cached h loads for s+1 (L2 shared by the XCD's 8 WGs)
      const u16* hcur = (s & 1) ? h0buf : h1buf;   // buffer written this step
      const u16* ap = hcur + (size_t)(mb + bi) * 1024 + quad * 8;
      ISSUE8(aA, 0);
      ISSUE8(aB, 8);
      ISSUE8(aC, 16);
      ISSUE8(aD, 24);
      SB0();
    }
  }
#pragma unroll
  for (int r = 0; r < 4; ++r) {
    int b = mb + quad * 4 + r;
    out[NOUT + (size_t)b * 1024 + jl] = hreg[r];
  }
}

extern "C" void kernel_launch(void* const* d_in, const int* in_sizes, int n_in,
                              void* d_out, int out_size, void* d_ws, size_t ws_size,
                              hipStream_t stream) {
  if (ws_size < WS_NEED) return;
  const float* x   = (const float*)d_in[0];
  const float* f0  = (const float*)d_in[1];
  const float* f1  = (const float*)d_in[2];
  const float* wih = (const float*)d_in[3];
  const float* whh = (const float*)d_in[4];
  const float* wf0 = (const float*)d_in[5];
  const float* wf1 = (const float*)d_in[6];
  const float* bih = (const float*)d_in[7];
  const float* bhh = (const float*)d_in[8];
  const float* bf0 = (const float*)d_in[9];
  const float* bf1 = (const float*)d_in[10];

  char* ws = (char*)d_ws;
  u16* gsum = (u16*)(ws + OFF_GSUM);
  u16* hb0 = (u16*)(ws + OFF_HB0);
  u16* hb1 = (u16*)(ws + OFF_HB1);
  unsigned* bar = (unsigned*)(ws + OFF_BAR);

  hipMemsetAsync(bar, 0, 128, stream);
  hipMemsetAsync(hb0, 0, 131072, stream);   // deterministic h buffers each launch
  hipMemsetAsync(hb1, 0, 131072, stream);

  gemm_fused<<<dim3(3072), dim3(256), 0, stream>>>(x, f0, f1, wih, wf0, wf1, bih, bf0, bf1, gsum);

  hipFuncSetAttribute(reinterpret_cast<const void*>(&scan_kernel),
                      hipFuncAttributeMaxDynamicSharedMemorySize, 98304);
  scan_kernel<<<dim3(64), dim3(256), 98304, stream>>>(gsum, whh, bhh, hb0, hb1, (float*)d_out, bar);
}

// Round 7
// 2234.369 us; speedup vs baseline: 1.3050x; 1.3050x over previous
//
#include <hip/hip_runtime.h>

typedef unsigned short u16;
typedef __attribute__((ext_vector_type(8))) short short8;
typedef __attribute__((ext_vector_type(4))) float f32x4;
typedef __attribute__((ext_vector_type(4))) unsigned u32x4;

// ---------- sizes ----------
#define BB 64
#define SS 256
#define HH 1024
#define NG 3072                 // 3H
#define KK 1024
#define NOUT ((size_t)BB * SS * HH)

// ws layout (bytes)
#define OFF_GSUM 0ull
#define OFF_HB0 100663296ull
#define OFF_HB1 100794368ull
#define OFF_BAR 100925440ull    // one 128B line: 8 split counters (offsets 0..28)
#define WS_NEED 100925568ull

__device__ __forceinline__ float bf2f_u(unsigned x) {
  unsigned u = x << 16;
  float f;
  __builtin_memcpy(&f, &u, 4);
  return f;
}
__device__ __forceinline__ u16 f2bf(float f) {
  unsigned u;
  __builtin_memcpy(&u, &f, 4);
  u = (u + 0x7fffu + ((u >> 16) & 1u)) >> 16;
  return (u16)u;
}
// pack 8 f32 -> short8 of bf16 (RTNE) via v_cvt_pk_bf16_f32
__device__ __forceinline__ short8 cvt8(f32x4 lo, f32x4 hi) {
  union { unsigned u[4]; short8 s; } r;
  asm("v_cvt_pk_bf16_f32 %0, %1, %2" : "=v"(r.u[0]) : "v"(lo[0]), "v"(lo[1]));
  asm("v_cvt_pk_bf16_f32 %0, %1, %2" : "=v"(r.u[1]) : "v"(lo[2]), "v"(lo[3]));
  asm("v_cvt_pk_bf16_f32 %0, %1, %2" : "=v"(r.u[2]) : "v"(hi[0]), "v"(hi[1]));
  asm("v_cvt_pk_bf16_f32 %0, %1, %2" : "=v"(r.u[3]) : "v"(hi[2]), "v"(hi[3]));
  return r.s;
}
__device__ __forceinline__ float sigmoidf_(float x) {
  return __builtin_amdgcn_rcpf(1.f + __expf(-x));
}
__device__ __forceinline__ float tanhf_(float x) {
  return 2.f * __builtin_amdgcn_rcpf(1.f + __expf(-2.f * x)) - 1.f;
}

typedef const __attribute__((address_space(1))) void* gcptr;
typedef __attribute__((address_space(3))) void* lptr;

// ================= GEMM (f32 inputs, bf16 MFMA): gsum = X@Wih^T + b_ih
//                   (+F0@Wf0^T + F1@Wf1^T + b_f0 + b_f1 on cols<2048)
// f32 tiles staged async via global_load_lds with XOR-swizzled SOURCE granules
// (LDS dest must stay linear); consume-side v_cvt_pk_bf16_f32 -> MFMA.
__global__ __launch_bounds__(256) void gemm_fused(
    const float* __restrict__ X, const float* __restrict__ F0, const float* __restrict__ F1,
    const float* __restrict__ Wih, const float* __restrict__ Wf0, const float* __restrict__ Wf1,
    const float* __restrict__ bih, const float* __restrict__ bf0, const float* __restrict__ bf1,
    u16* __restrict__ C) {
  __shared__ __align__(16) float ldsA[128 * 32];
  __shared__ __align__(16) float ldsB[128 * 32];
  const int t = threadIdx.x;
  const int nwg = gridDim.x;                  // 3072 (divisible by 8)
  const int cpx = nwg >> 3;
  const int wg = (blockIdx.x & 7) * cpx + (blockIdx.x >> 3);   // XCD-contiguous chunks
  const int ntn = NG / 128;                   // 24
  const int m0 = (wg / ntn) * 128;
  const int n0 = (wg % ntn) * 128;
  const int lane = t & 63, wv = t >> 6;
  const int wm = wv >> 1, wn = wv & 1;

  f32x4 acc[4][4] = {};

  const int nsrc = (n0 < 2048) ? 3 : 1;
  for (int src = 0; src < nsrc; ++src) {
    const float* Ap = (src == 0) ? X : ((src == 1) ? F0 : F1);
    const float* Wp = (src == 0) ? Wih : ((src == 1) ? Wf0 : Wf1);
    const float* Abase = Ap + (size_t)m0 * KK;
    const float* Wbase = Wp + (size_t)n0 * KK;
    for (int k0 = 0; k0 < KK; k0 += 32) {
#pragma unroll
      for (int c = 0; c < 4; ++c) {
        const int idx = c * 256 + t;
        const int row = idx >> 3, q = idx & 7;
        const int qs = q ^ (row & 7);
        __builtin_amdgcn_global_load_lds((gcptr)(Abase + (size_t)row * KK + k0 + qs * 4),
                                         (lptr)(&ldsA[idx * 4]), 16, 0, 0);
        __builtin_amdgcn_global_load_lds((gcptr)(Wbase + (size_t)row * KK + k0 + qs * 4),
                                         (lptr)(&ldsB[idx * 4]), 16, 0, 0);
      }
      __syncthreads();
      short8 af[4], bw[4];
      const int g0 = (lane >> 4) * 2;      // granule pair base for this lane
#pragma unroll
      for (int i = 0; i < 4; ++i) {
        {
          const int row = wm * 64 + i * 16 + (lane & 15);
          const int ga = g0 ^ (row & 7), gb = (g0 + 1) ^ (row & 7);
          f32x4 lo = *(const f32x4*)&ldsA[row * 32 + ga * 4];
          f32x4 hi = *(const f32x4*)&ldsA[row * 32 + gb * 4];
          af[i] = cvt8(lo, hi);
        }
        {
          const int row = wn * 64 + i * 16 + (lane & 15);
          const int ga = g0 ^ (row & 7), gb = (g0 + 1) ^ (row & 7);
          f32x4 lo = *(const f32x4*)&ldsB[row * 32 + ga * 4];
          f32x4 hi = *(const f32x4*)&ldsB[row * 32 + gb * 4];
          bw[i] = cvt8(lo, hi);
        }
      }
#pragma unroll
      for (int i = 0; i < 4; ++i)
#pragma unroll
        for (int j = 0; j < 4; ++j)
          acc[i][j] = __builtin_amdgcn_mfma_f32_16x16x32_bf16(af[i], bw[j], acc[i][j], 0, 0, 0);
      __syncthreads();
    }
  }
#pragma unroll
  for (int j = 0; j < 4; ++j) {
    const int col = n0 + wn * 64 + j * 16 + (lane & 15);
    float bias = bih[col];
    if (col < 2048) bias += bf0[col] + bf1[col];
#pragma unroll
    for (int i = 0; i < 4; ++i) {
      const int row = m0 + wm * 64 + i * 16 + (lane >> 4) * 4;
#pragma unroll
      for (int r = 0; r < 4; ++r)
        C[(size_t)(row + r) * NG + col] = f2bf(acc[i][j][r] + bias);
    }
  }
}

// ================= scan: weight-stationary persistent GRU ====================
// 64 WGs x 256 thr. WG w owns hidden cols [w*16, w*16+16). Whh strips r,i,n in LDS
// as [48 rows][2048B], full-rank XOR swizzle -> conflict-free (measured 0).
// h exchange: sc0/sc1 write-through stores + sc0/sc1 bypass loads (R5 semantics;
// NO fences -- R6 proved the per-step acquire fence costs ~2.6us/step).
// Barrier: 8 split counters in one line (blockIdx&7 groups) -> arrivals
// parallelize if MALL serializes atomics per-address; spin = 2x dwordx4 + sum.
#define SB0() __builtin_amdgcn_sched_barrier(0)

#define ISSUE8(buf, bkk)                                                        \
  _Pragma("unroll")                                                             \
  for (int i_ = 0; i_ < 8; ++i_)                                                \
    asm volatile("global_load_dwordx4 %0, %1, off sc0 sc1"                      \
                 : "=v"(buf[i_]) : "v"(ap + ((bkk) + i_) * 32));

#define CONSUME8(buf, bkk)                                                      \
  _Pragma("unroll")                                                             \
  for (int i_ = 0; i_ < 8; ++i_) {                                              \
    const int ko_ = ((bkk) + i_) * 64 + kb;                                     \
    short8 br_ = *(const short8*)(s0 + (ko_ ^ sw));                             \
    short8 bj_ = *(const short8*)(s1 + (ko_ ^ sw));                             \
    short8 bn_ = *(const short8*)(s2 + (ko_ ^ sw));                             \
    ar = __builtin_amdgcn_mfma_f32_16x16x32_bf16(buf[i_], br_, ar, 0, 0, 0);    \
    ai = __builtin_amdgcn_mfma_f32_16x16x32_bf16(buf[i_], bj_, ai, 0, 0, 0);    \
    an = __builtin_amdgcn_mfma_f32_16x16x32_bf16(buf[i_], bn_, an, 0, 0, 0);    \
  }

#define ISSUE_GSUM(snext)                                                       \
  _Pragma("unroll")                                                             \
  for (int r_ = 0; r_ < 4; ++r_) {                                              \
    const u16* gp_ = gsum + ((size_t)(mb + quad * 4 + r_) * 256 + (size_t)(snext)) * 3072 + jl; \
    asm volatile("global_load_ushort %0, %1, off" : "=v"(pgu[r_ * 3 + 0]) : "v"(gp_));          \
    asm volatile("global_load_ushort %0, %1, off" : "=v"(pgu[r_ * 3 + 1]) : "v"(gp_ + 1024));   \
    asm volatile("global_load_ushort %0, %1, off" : "=v"(pgu[r_ * 3 + 2]) : "v"(gp_ + 2048));   \
  }

__global__ __launch_bounds__(256, 1) void scan_kernel(
    const u16* __restrict__ gsum, const float* __restrict__ Whh, const float* __restrict__ bhh,
    u16* __restrict__ h0buf, u16* __restrict__ h1buf,
    float* __restrict__ out, unsigned* __restrict__ bar) {
  extern __shared__ u16 wlds[];  // 48*1024 bf16 = 96KB
  const int t = threadIdx.x, w = blockIdx.x;
  const int j0 = w * 16;
  // stage weights (once): row q = g*16+i <- Whh[g*1024 + j0 + i][:], f32 -> bf16, byte ^= (i<<4)
  for (int c = t; c < 48 * 128; c += 256) {
    int q = c >> 7, chunk = c & 127;
    int g = q >> 4, i = q & 15;
    const float* wf = Whh + ((size_t)(g * 1024 + j0 + i)) * 1024 + chunk * 8;
    short8 v = cvt8(*(const f32x4*)wf, *(const f32x4*)(wf + 4));
    *(short8*)((char*)wlds + q * 2048 + ((chunk * 16) ^ (i << 4))) = v;
  }
  const int lane = t & 63;
  const int bi = lane & 15;
  const int quad = lane >> 4;
  const int jl = j0 + bi;
  const int mb = (t >> 6) * 16;
  const float bhr = bhh[jl];
  const float bhi = bhh[1024 + jl];
  const float bhn = bhh[2048 + jl];
  __syncthreads();

  float hreg[4] = {0.f, 0.f, 0.f, 0.f};

  const int kb = quad * 16;                 // byte offset of lane's 16B k-chunk
  const int sw = bi << 4;                   // full-rank XOR swizzle
  const char* wbytes = (const char*)wlds;
  const char* s0 = wbytes + (size_t)(0 + bi) * 2048;
  const char* s1 = wbytes + (size_t)(16 + bi) * 2048;
  const char* s2 = wbytes + (size_t)(32 + bi) * 2048;

  unsigned* myctr = bar + (w & 7);          // split arrive counter (8 per group)

  unsigned pgu[12];
  ISSUE_GSUM(0);
  asm volatile("s_waitcnt vmcnt(0)" ::: "memory");
  SB0();

  short8 aA[8], aB[8], aC[8], aD[8];
  for (int s = 0; s < 256; ++s) {
    f32x4 ar = {0.f, 0.f, 0.f, 0.f};
    f32x4 ai = {0.f, 0.f, 0.f, 0.f};
    f32x4 an = {0.f, 0.f, 0.f, 0.f};
    if (s > 0) {
      // outstanding: 16 older (4 out + 12 gsum) then 32 h loads -> counted consume
      asm volatile("s_waitcnt vmcnt(24)" ::: "memory");
      SB0();
      CONSUME8(aA, 0);
      asm volatile("s_waitcnt vmcnt(16)" ::: "memory");
      SB0();
      CONSUME8(aB, 8);
      asm volatile("s_waitcnt vmcnt(8)" ::: "memory");
      SB0();
      CONSUME8(aC, 16);
      asm volatile("s_waitcnt vmcnt(0)" ::: "memory");
      SB0();
      CONSUME8(aD, 24);
      SB0();
    }
    u16* hw = (s & 1) ? h0buf : h1buf;
    float hy4[4];
    unsigned hv4[4];
#pragma unroll
    for (int r = 0; r < 4; ++r) {
      float rg = sigmoidf_(bf2f_u(pgu[r * 3 + 0]) + ar[r] + bhr);
      float ig = sigmoidf_(bf2f_u(pgu[r * 3 + 1]) + ai[r] + bhi);
      float ng = tanhf_(bf2f_u(pgu[r * 3 + 2]) + rg * (an[r] + bhn));
      float hy = ng + ig * (hreg[r] - ng);
      hreg[r] = hy;
      hy4[r] = hy;
      hv4[r] = (unsigned)f2bf(hy);
    }
    // ALL 4 h stores first (so vmcnt(16) retires exactly them), then 4 out stores.
    if (s < 255) {
#pragma unroll
      for (int r = 0; r < 4; ++r) {
        int b = mb + quad * 4 + r;
        asm volatile("global_store_short %0, %1, off sc0 sc1"
                     :: "v"(hw + (size_t)b * 1024 + jl), "v"(hv4[r]) : "memory");
      }
    }
#pragma unroll
    for (int r = 0; r < 4; ++r) {
      int b = mb + quad * 4 + r;
      size_t m = (size_t)b * 256 + s;
      asm volatile("global_store_dword %0, %1, off nt"
                   :: "v"(out + m * 1024 + jl), "v"(hy4[r]) : "memory");
    }
    if (s < 255) {
      ISSUE_GSUM(s + 1);
      // outstanding: [4 hst][4 out][12 gsum] -> vmcnt(16) retires exactly the h stores
      asm volatile("s_waitcnt vmcnt(16)" ::: "memory");
      SB0();
      __builtin_amdgcn_s_barrier();          // raw: no compiler vmcnt(0) drain
      if (t == 0) {
        unsigned one = 1;
        asm volatile("global_atomic_add %0, %1, off" :: "v"(myctr), "v"(one) : "memory");
        const unsigned target = 64u * (unsigned)(s + 1);
        for (;;) {
          u32x4 va, vb;
          asm volatile("global_load_dwordx4 %0, %2, off sc0 sc1\n\t"
                       "global_load_dwordx4 %1, %3, off sc0 sc1\n\t"
                       "s_waitcnt vmcnt(0)"
                       : "=v"(va), "=v"(vb) : "v"(bar), "v"(bar + 4) : "memory");
          unsigned sum = va[0] + va[1] + va[2] + va[3] + vb[0] + vb[1] + vb[2] + vb[3];
          if (sum >= target) break;
          __builtin_amdgcn_s_sleep(1);
        }
      }
      __builtin_amdgcn_s_barrier();
      SB0();
      // issue bypass h loads for s+1 (consumed at top of next iter)
      const u16* hcur = (s & 1) ? h0buf : h1buf;   // buffer written this step
      const u16* ap = hcur + (size_t)(mb + bi) * 1024 + quad * 8;
      ISSUE8(aA, 0);
      ISSUE8(aB, 8);
      ISSUE8(aC, 16);
      ISSUE8(aD, 24);
      SB0();
    }
  }
#pragma unroll
  for (int r = 0; r < 4; ++r) {
    int b = mb + quad * 4 + r;
    out[NOUT + (size_t)b * 1024 + jl] = hreg[r];
  }
}

extern "C" void kernel_launch(void* const* d_in, const int* in_sizes, int n_in,
                              void* d_out, int out_size, void* d_ws, size_t ws_size,
                              hipStream_t stream) {
  if (ws_size < WS_NEED) return;
  const float* x   = (const float*)d_in[0];
  const float* f0  = (const float*)d_in[1];
  const float* f1  = (const float*)d_in[2];
  const float* wih = (const float*)d_in[3];
  const float* whh = (const float*)d_in[4];
  const float* wf0 = (const float*)d_in[5];
  const float* wf1 = (const float*)d_in[6];
  const float* bih = (const float*)d_in[7];
  const float* bhh = (const float*)d_in[8];
  const float* bf0 = (const float*)d_in[9];
  const float* bf1 = (const float*)d_in[10];

  char* ws = (char*)d_ws;
  u16* gsum = (u16*)(ws + OFF_GSUM);
  u16* hb0 = (u16*)(ws + OFF_HB0);
  u16* hb1 = (u16*)(ws + OFF_HB1);
  unsigned* bar = (unsigned*)(ws + OFF_BAR);

  hipMemsetAsync(bar, 0, 128, stream);
  hipMemsetAsync(hb0, 0, 131072, stream);   // deterministic h buffers each launch
  hipMemsetAsync(hb1, 0, 131072, stream);

  gemm_fused<<<dim3(3072), dim3(256), 0, stream>>>(x, f0, f1, wih, wf0, wf1, bih, bf0, bf1, gsum);

  hipFuncSetAttribute(reinterpret_cast<const void*>(&scan_kernel),
                      hipFuncAttributeMaxDynamicSharedMemorySize, 98304);
  scan_kernel<<<dim3(64), dim3(256), 98304, stream>>>(gsum, whh, bhh, hb0, hb1, (float*)d_out, bar);
}